// Round 11
// baseline (280.872 us; speedup 1.0000x reference)
//
#include <hip/hip_runtime.h>
#include <stdint.h>

// Problem constants (match reference)
constexpr int B = 4, C = 16, H = 512, W = 512;
constexpr int N = H * W;                   // pixels per batch plane (262144)
constexpr int BLOCKS_PER_BATCH = N / 256;  // 1024
constexpr int NXCD = 8;
constexpr float EPS = 1e-10f;

// PULL-MODEL rewrite — zero scattered global updates.
// R9/R10 established the wall: address-divergent per-lane global
// updates (stores OR atomics, any scope, warm or cold) process at
// ~1/cycle/XCD => 0.7M updates = ~35us, invariant to everything
// (R0 stores, R3 atomicMin u32, R7 u64 +15%, R10 per-XCD workgroup
// scope — all identical). Escape = don't scatter to global at all:
//   P1 project_rec: R3's kernel, tail writes recs[n]=(t<<32)|z
//       fully coalesced (no atomics). ~10us.
//   P2 slab_resolve: 64 blocks; each OWNS a disjoint 32-row target
//       slab (16K cells, 64KB LDS). Scans the whole batch's recs
//       (2MB coalesced, L2/L3-resident), atomicMin into LDS
//       (banked; +-1 shfl run-dedup kills border-clamp hotspots),
//       then writes final out[] directly: plain coalesced stores,
//       disjoint slabs, no races, fused resolve (-1 dispatch).
// Winner rule: max source n == min key (key = N-1-n); z rides in
// rec low word. No reliance on ws poison anymore.
// Ledger (falsified): R1 L2-locality swizzle; R2 traffic volume; R3
// mask latency-chain; R5 PPT=4 (occupancy); R6 L1-set aliasing; R7
// vmem-instr count; R9 attribution (scatter stream = the wall); R10
// atomic scope/XCD-locality. R8(prev): grid.sync ~100us. R10(prev):
// nontemporal regresses. Fill (41us, 256MB harness poison) = fixed.

__device__ __forceinline__ void swizzle_bn(int orig, int& b, int& blk) {
    // Perf heuristic only; correctness is mapping-independent.
    int xcd = orig & (NXCD - 1);
    int j   = orig >> 3;               // 0..511
    b       = j >> 7;                  // 0..3   (batch)
    int r   = j & 127;                 // 0..127
    blk     = xcd * 128 + r;           // 0..1023
}

// P1: projection -> recs[n] = (target<<32) | zbits, fully coalesced.
__global__ __launch_bounds__(256) void project_rec_kernel(
    const float* __restrict__ depth,   // [B,1,H,W]
    const float* __restrict__ K,       // [B,3,3]
    const float* __restrict__ T,       // [B,C,4,4]
    const int*   __restrict__ masks,   // [B,C,H,W] (0/1)
    unsigned long long* __restrict__ recs)  // [B,N]
{
    __shared__ float Ts[16][17];       // Ts[e][c] = T[b][c][e]

    int b, blk;
    swizzle_bn(blockIdx.x, b, blk);
    int t = threadIdx.x;
    int n = (blk << 8) + t;
    int idx = b * N + n;
    int v = n >> 9;                    // n / W
    int u = n & (W - 1);               // n % W

    // --- issue ALL independent global loads FIRST (R3 flat scan) ---
    float d = depth[idx];
    const int* mb = masks + (size_t)b * C * N + n;
    int m[16];
    #pragma unroll
    for (int c = 0; c < 16; ++c) m[c] = mb[(size_t)c * N];

    // stage T[b] (256 floats) into LDS, transposed
    {
        int c = t >> 4, e = t & 15;
        Ts[e][c] = T[(size_t)b * 256 + t];
    }
    __syncthreads();

    // --- branchless priority select: highest set channel wins ---
    unsigned bm = 0;
    #pragma unroll
    for (int c = 0; c < 16; ++c) bm |= (m[c] ? 1u : 0u) << c;
    int sel = bm ? (31 - __clz(bm)) : -1;

    // --- K[b] (block-uniform scalar loads) ---
    const float* Kb = K + b * 9;
    float k00 = Kb[0], k01 = Kb[1], k02 = Kb[2];
    float k10 = Kb[3], k11 = Kb[4], k12 = Kb[5];
    float k20 = Kb[6], k21 = Kb[7], k22 = Kb[8];

    // adjugate inverse
    float c00 =  (k11 * k22 - k12 * k21);
    float c01 = -(k10 * k22 - k12 * k20);
    float c02 =  (k10 * k21 - k11 * k20);
    float det = k00 * c00 + k01 * c01 + k02 * c02;
    float invdet = 1.0f / det;
    float i00 =  (k11 * k22 - k12 * k21) * invdet;
    float i01 = -(k01 * k22 - k02 * k21) * invdet;
    float i02 =  (k01 * k12 - k02 * k11) * invdet;
    float i10 = -(k10 * k22 - k12 * k20) * invdet;
    float i11 =  (k00 * k22 - k02 * k20) * invdet;
    float i12 = -(k00 * k12 - k02 * k10) * invdet;
    float i20 =  (k10 * k21 - k11 * k20) * invdet;
    float i21 = -(k00 * k21 - k01 * k20) * invdet;
    float i22 =  (k00 * k11 - k01 * k10) * invdet;

    float uf = (float)u, vf = (float)v;
    float px = (i00 * uf + i01 * vf + i02) * d;
    float py = (i10 * uf + i11 * vf + i12) * d;
    float pz = (i20 * uf + i21 * vf + i22) * d;

    float ox = px, oy = py, oz = pz;
    if (sel >= 0) {
        float tx = Ts[0][sel]*px + Ts[1][sel]*py + Ts[2][sel]*pz + Ts[3][sel];
        float ty = Ts[4][sel]*px + Ts[5][sel]*py + Ts[6][sel]*pz + Ts[7][sel];
        float tz = Ts[8][sel]*px + Ts[9][sel]*py + Ts[10][sel]*pz + Ts[11][sel];
        float tw = Ts[12][sel]*px + Ts[13][sel]*py + Ts[14][sel]*pz + Ts[15][sel];
        float denom = tw + EPS;
        ox = tx / denom;
        oy = ty / denom;
        oz = tz / denom;
    }

    // --- reproject with K ---
    float qx = k00 * ox + k01 * oy + k02 * oz;
    float qy = k10 * ox + k11 * oy + k12 * oz;
    float qz = k20 * ox + k21 * oy + k22 * oz;
    float zz = qz + EPS;
    float pu = qx / zz;
    float pv = qy / zz;
    pu = fminf(fmaxf(pu, 0.0f), (float)(W - 1));
    pv = fminf(fmaxf(pv, 0.0f), (float)(H - 1));
    int ui = (int)pu;
    int vi = (int)pv;
    unsigned tg = (unsigned)(vi * W + ui);

    // coalesced u64 store — NO scattered update
    recs[idx] = ((unsigned long long)tg << 32)
              | (unsigned long long)__float_as_uint(oz);
}

// P2: slab-owner pull + fused resolve. 64 blocks = 4 batches x 16 slabs
// (32 target rows each). No global atomics, no races (disjoint slabs).
constexpr int SLAB_CELLS = 32 * W;         // 16384 cells = 64 KB LDS
constexpr int P2_THREADS = 512;

__global__ __launch_bounds__(P2_THREADS) void slab_resolve_kernel(
    const unsigned long long* __restrict__ recs,   // [B,N]
    const float*              __restrict__ depth,  // [B,1,H,W]
    float*                    __restrict__ out)    // [B,1,H,W]
{
    __shared__ unsigned skey[SLAB_CELLS];

    int bid  = blockIdx.x;
    int b    = bid >> 4;               // batch
    int slab = bid & 15;               // 32-row slab within batch
    int tid  = threadIdx.x;
    int lane = tid & 63;

    #pragma unroll
    for (int j = tid; j < SLAB_CELLS; j += P2_THREADS)
        skey[j] = 0xFFFFFFFFu;
    __syncthreads();

    const unsigned long long* rb = recs + (size_t)b * N;

    // Scan all sources of this batch; keep hits in our slab.
    // +-1 shfl run-dedup: a same-target rec at i+1 (larger n -> smaller
    // key) dominates ours; runs (border-clamp hotspots) collapse to
    // their last element. Under-elision is always safe.
    for (int i = tid; i < N; i += P2_THREADS) {
        unsigned long long r = rb[i];
        unsigned t = (unsigned)(r >> 32);
        unsigned tn = (unsigned)__shfl_down((int)t, 1);
        bool skip = (lane < 63) && (tn == t);
        if (!skip && (t >> 14) == (unsigned)slab) {
            atomicMin(&skey[t & (SLAB_CELLS - 1)], (unsigned)(N - 1 - i));
        }
    }
    __syncthreads();

    // Fused resolve: plain coalesced stores of the final output.
    int out0 = b * N + slab * SLAB_CELLS;
    for (int j = tid; j < SLAB_CELLS; j += P2_THREADS) {
        unsigned k = skey[j];
        float val;
        if (k != 0xFFFFFFFFu) {
            int n_w = N - 1 - (int)k;                  // winner source
            val = __uint_as_float((unsigned)rb[n_w]);  // z in low word
        } else {
            val = depth[out0 + j];
        }
        out[out0 + j] = val;
    }
}

extern "C" void kernel_launch(void* const* d_in, const int* in_sizes, int n_in,
                              void* d_out, int out_size, void* d_ws, size_t ws_size,
                              hipStream_t stream) {
    const float* depth = (const float*)d_in[0];   // [B,1,H,W] fp32
    const float* K     = (const float*)d_in[1];   // [B,3,3]   fp32
    const float* T     = (const float*)d_in[2];   // [B,C,4,4] fp32
    const int*   masks = (const int*)d_in[3];     // [B,C,H,W] int32 0/1
    float* out = (float*)d_out;                    // [B,1,H,W] fp32

    unsigned long long* recs = (unsigned long long*)d_ws;   // 8 MB

    project_rec_kernel<<<B * BLOCKS_PER_BATCH, 256, 0, stream>>>(
        depth, K, T, masks, recs);
    slab_resolve_kernel<<<B * 16, P2_THREADS, 0, stream>>>(recs, depth, out);
}

// Round 12
// 142.170 us; speedup vs baseline: 1.9756x; 1.9756x over previous
//
#include <hip/hip_runtime.h>
#include <stdint.h>

// Problem constants (match reference)
constexpr int B = 4, C = 16, H = 512, W = 512;
constexpr int N = H * W;                   // pixels per batch plane (262144)
constexpr int BLOCKS_PER_BATCH = N / 256;  // 1024
constexpr int NXCD = 8;
constexpr float EPS = 1e-10f;

// PULL MODEL v2 — zero scattered global updates, starvation fixed.
// R9/R10: address-divergent per-lane global updates (stores OR atomics,
// any scope) process at ~1 update/cyc/XCD => 0.7M updates = ~35us wall.
// R11: pull v1 removed the wall (project_rec < 41us cutoff ✓) but P2
// starved: 64 blocks (25% of CUs), 1 block/CU, 512 dependent load
// rounds => 187us. v2 fixes exactly that:
//   - 16-row slabs (32KB LDS), 32 slabs/batch, G=4 scan chunks/slab
//     => 512 blocks, >=2/CU.
//   - explicit 8-wide strided unroll: 8 independent coalesced u64
//     loads in flight per round (32 rounds, latency-hidden).
//   - XCD<->batch mapping: each batch's 2MB recs scanned by 2 XCDs
//     => L2-resident amplified reads (256MB total at ~34TB/s agg).
//   - P3 merges the G tables per slab (coalesced) + resolves.
// Winner rule: max source n == min key (key = N-1-n); z in rec low
// word. Tables LDS-init to +inf — no reliance on ws poison.
// Ledger (falsified): R1 L2-locality swizzle (neutral, kept); R2
// traffic volume; R3 mask latency-chain; R5 PPT=4 (occupancy); R6
// L1-set aliasing; R7 vmem-instr count (+u64 atomic +15%); R10 atomic
// scope/XCD-locality; R11 pull-v1 starvation (fixed here).
// Budget model: total = fill(41, fixed) + ~8us/dispatch + sum(kernels).

__device__ __forceinline__ void swizzle_bn(int orig, int& b, int& blk) {
    // Perf heuristic only; correctness is mapping-independent.
    int xcd = orig & (NXCD - 1);
    int j   = orig >> 3;               // 0..511
    b       = j >> 7;                  // 0..3   (batch)
    int r   = j & 127;                 // 0..127
    blk     = xcd * 128 + r;           // 0..1023
}

// P1: projection -> recs[n] = (target<<32) | zbits, fully coalesced.
__global__ __launch_bounds__(256) void project_rec_kernel(
    const float* __restrict__ depth,   // [B,1,H,W]
    const float* __restrict__ K,       // [B,3,3]
    const float* __restrict__ T,       // [B,C,4,4]
    const int*   __restrict__ masks,   // [B,C,H,W] (0/1)
    unsigned long long* __restrict__ recs)  // [B,N]
{
    __shared__ float Ts[16][17];       // Ts[e][c] = T[b][c][e]

    int b, blk;
    swizzle_bn(blockIdx.x, b, blk);
    int t = threadIdx.x;
    int n = (blk << 8) + t;
    int idx = b * N + n;
    int v = n >> 9;                    // n / W
    int u = n & (W - 1);               // n % W

    // --- issue ALL independent global loads FIRST (R3 flat scan) ---
    float d = depth[idx];
    const int* mb = masks + (size_t)b * C * N + n;
    int m[16];
    #pragma unroll
    for (int c = 0; c < 16; ++c) m[c] = mb[(size_t)c * N];

    // stage T[b] (256 floats) into LDS, transposed
    {
        int c = t >> 4, e = t & 15;
        Ts[e][c] = T[(size_t)b * 256 + t];
    }
    __syncthreads();

    // --- branchless priority select: highest set channel wins ---
    unsigned bm = 0;
    #pragma unroll
    for (int c = 0; c < 16; ++c) bm |= (m[c] ? 1u : 0u) << c;
    int sel = bm ? (31 - __clz(bm)) : -1;

    // --- K[b] (block-uniform scalar loads) ---
    const float* Kb = K + b * 9;
    float k00 = Kb[0], k01 = Kb[1], k02 = Kb[2];
    float k10 = Kb[3], k11 = Kb[4], k12 = Kb[5];
    float k20 = Kb[6], k21 = Kb[7], k22 = Kb[8];

    // adjugate inverse
    float c00 =  (k11 * k22 - k12 * k21);
    float c01 = -(k10 * k22 - k12 * k20);
    float c02 =  (k10 * k21 - k11 * k20);
    float det = k00 * c00 + k01 * c01 + k02 * c02;
    float invdet = 1.0f / det;
    float i00 =  (k11 * k22 - k12 * k21) * invdet;
    float i01 = -(k01 * k22 - k02 * k21) * invdet;
    float i02 =  (k01 * k12 - k02 * k11) * invdet;
    float i10 = -(k10 * k22 - k12 * k20) * invdet;
    float i11 =  (k00 * k22 - k02 * k20) * invdet;
    float i12 = -(k00 * k12 - k02 * k10) * invdet;
    float i20 =  (k10 * k21 - k11 * k20) * invdet;
    float i21 = -(k00 * k21 - k01 * k20) * invdet;
    float i22 =  (k00 * k11 - k01 * k10) * invdet;

    float uf = (float)u, vf = (float)v;
    float px = (i00 * uf + i01 * vf + i02) * d;
    float py = (i10 * uf + i11 * vf + i12) * d;
    float pz = (i20 * uf + i21 * vf + i22) * d;

    float ox = px, oy = py, oz = pz;
    if (sel >= 0) {
        float tx = Ts[0][sel]*px + Ts[1][sel]*py + Ts[2][sel]*pz + Ts[3][sel];
        float ty = Ts[4][sel]*px + Ts[5][sel]*py + Ts[6][sel]*pz + Ts[7][sel];
        float tz = Ts[8][sel]*px + Ts[9][sel]*py + Ts[10][sel]*pz + Ts[11][sel];
        float tw = Ts[12][sel]*px + Ts[13][sel]*py + Ts[14][sel]*pz + Ts[15][sel];
        float denom = tw + EPS;
        ox = tx / denom;
        oy = ty / denom;
        oz = tz / denom;
    }

    // --- reproject with K ---
    float qx = k00 * ox + k01 * oy + k02 * oz;
    float qy = k10 * ox + k11 * oy + k12 * oz;
    float qz = k20 * ox + k21 * oy + k22 * oz;
    float zz = qz + EPS;
    float pu = qx / zz;
    float pv = qy / zz;
    pu = fminf(fmaxf(pu, 0.0f), (float)(W - 1));
    pv = fminf(fmaxf(pv, 0.0f), (float)(H - 1));
    int ui = (int)pu;
    int vi = (int)pv;
    unsigned tg = (unsigned)(vi * W + ui);

    // coalesced u64 store — NO scattered update
    recs[idx] = ((unsigned long long)tg << 32)
              | (unsigned long long)__float_as_uint(oz);
}

// P2: slab scan. 512 blocks = B(4) x SLABS(32) x G(4). Each block scans
// chunk g of its batch's recs into a 32KB LDS key table for its slab.
constexpr int SLAB_ROWS  = 16;
constexpr int SLAB_CELLS = SLAB_ROWS * W;   // 8192 cells = 32 KB LDS
constexpr int SLABS      = H / SLAB_ROWS;   // 32 per batch
constexpr int G          = 4;               // scan chunks per slab
constexpr int CHUNK      = N / G;           // 65536 sources
constexpr int P2_T       = 256;

__global__ __launch_bounds__(P2_T) void scan_kernel(
    const unsigned long long* __restrict__ recs,   // [B,N]
    unsigned* __restrict__ tables)  // [B][SLABS][G][SLAB_CELLS]
{
    __shared__ unsigned skey[SLAB_CELLS];

    // xcd<->batch mapping (round-robin heuristic): batch b's 128 blocks
    // land on XCDs {2b, 2b+1} so its 2MB recs plane stays L2-resident.
    int bid  = blockIdx.x;             // 0..511
    int xcd  = bid & 7;
    int b    = xcd >> 1;
    int j    = ((xcd & 1) << 6) | (bid >> 3);  // 0..127
    int slab = j >> 2;                 // 0..31
    int g    = j & 3;                  // 0..3
    int tid  = threadIdx.x;
    int lane = tid & 63;

    #pragma unroll
    for (int c = tid; c < SLAB_CELLS; c += P2_T) skey[c] = 0xFFFFFFFFu;
    __syncthreads();

    const unsigned long long* rb = recs + (size_t)b * N + (size_t)g * CHUNK;

    // 32 rounds x 8 independent coalesced loads (latency-hidden).
    for (int r = 0; r < CHUNK / (P2_T * 8); ++r) {
        int base = r * (P2_T * 8) + tid;
        unsigned long long v[8];
        #pragma unroll
        for (int k = 0; k < 8; ++k) v[k] = rb[base + k * P2_T];
        #pragma unroll
        for (int k = 0; k < 8; ++k) {
            unsigned t = (unsigned)(v[k] >> 32);
            // +-1 run-dedup: lane+1 holds source n+1 (larger n -> smaller
            // key) — same target => ours is dominated. Under-elision safe.
            unsigned tn = (unsigned)__shfl_down((int)t, 1);
            bool skip = (lane < 63) && (tn == t);
            if (!skip && (t >> 13) == (unsigned)slab) {
                int i = g * CHUNK + base + k * P2_T;   // source n
                atomicMin(&skey[t & (SLAB_CELLS - 1)], (unsigned)(N - 1 - i));
            }
        }
    }
    __syncthreads();

    // coalesced table dump
    unsigned* tb = tables + ((((size_t)b * SLABS + slab) * G + g) << 13);
    #pragma unroll
    for (int c = tid; c < SLAB_CELLS; c += P2_T) tb[c] = skey[c];
}

// P3: merge G tables per slab (coalesced) + resolve output.
__global__ __launch_bounds__(256) void merge_resolve_kernel(
    const unsigned*           __restrict__ tables,
    const unsigned long long* __restrict__ recs,
    const float*              __restrict__ depth,
    float*                    __restrict__ out)
{
    int idx = blockIdx.x * 256 + threadIdx.x;
    if (idx >= B * N) return;
    int b    = idx >> 18;              // N = 2^18
    int t    = idx & (N - 1);
    int slab = t >> 13;
    int cell = t & (SLAB_CELLS - 1);

    const unsigned* tb = tables + ((((size_t)b * SLABS + slab) * G) << 13);
    unsigned k0 = min(tb[cell],                  tb[cell + SLAB_CELLS]);
    unsigned k1 = min(tb[cell + 2 * SLAB_CELLS], tb[cell + 3 * SLAB_CELLS]);
    unsigned kmin = min(k0, k1);

    float val;
    if (kmin != 0xFFFFFFFFu) {
        int n_w = N - 1 - (int)kmin;               // winner source
        val = __uint_as_float((unsigned)recs[(size_t)b * N + n_w]);
    } else {
        val = depth[idx];
    }
    out[idx] = val;
}

extern "C" void kernel_launch(void* const* d_in, const int* in_sizes, int n_in,
                              void* d_out, int out_size, void* d_ws, size_t ws_size,
                              hipStream_t stream) {
    const float* depth = (const float*)d_in[0];   // [B,1,H,W] fp32
    const float* K     = (const float*)d_in[1];   // [B,3,3]   fp32
    const float* T     = (const float*)d_in[2];   // [B,C,4,4] fp32
    const int*   masks = (const int*)d_in[3];     // [B,C,H,W] int32 0/1
    float* out = (float*)d_out;                    // [B,1,H,W] fp32

    char* ws = (char*)d_ws;
    unsigned long long* recs = (unsigned long long*)ws;          // 8 MB
    unsigned* tables = (unsigned*)(ws + (size_t)B * N * 8);      // 16 MB

    project_rec_kernel<<<B * BLOCKS_PER_BATCH, 256, 0, stream>>>(
        depth, K, T, masks, recs);
    scan_kernel<<<B * SLABS * G, P2_T, 0, stream>>>(recs, tables);
    merge_resolve_kernel<<<B * N / 256, 256, 0, stream>>>(
        tables, recs, depth, out);
}